// Round 8
// baseline (367.397 us; speedup 1.0000x reference)
//
#include <hip/hip_runtime.h>
#include <hip/hip_bf16.h>

#define BIGV 1.0e9f

static constexpr int B_ = 32;
static constexpr int L_ = 1024;
static constexpr int F_ = 128;
static constexpr int S_ = 4;          // in-wave lane stagger (columns)
static constexpr int UDIM_ = 1296;    // skewed u-rows per stream (1275 used + ring slack)
static constexpr int LAG_ = 288;      // wave1 local-step lag (18 phases; multiple of 16)
static constexpr int NSEGG_ = 98;     // global phases (1568 steps)
static constexpr size_t STREAM_US = (size_t)B_ * 2 * UDIM_ * 512;  // ushorts

typedef __attribute__((ext_vector_type(8))) short short8;
typedef __attribute__((ext_vector_type(4))) float f32x4;

__device__ __forceinline__ unsigned pack2(float x, float y) {
  union { float f; unsigned u; } a, b;
  a.f = x; b.f = y;
  unsigned lo = (a.u + 0x7FFFu + ((a.u >> 16) & 1u)) >> 16;
  unsigned hi = (b.u + 0x7FFFu + ((b.u >> 16) & 1u)) >> 16;
  return lo | (hi << 16);
}

// one wave per row of 128 floats; nrm[wid] = sum of squares
__global__ void norm_kernel(const float* __restrict__ s1, const float* __restrict__ s2,
                            float* __restrict__ nrm) {
  int gt   = blockIdx.x * blockDim.x + threadIdx.x;
  int wid  = gt >> 6;
  int lane = gt & 63;
  const float* src = (wid < B_ * L_) ? (s1 + (size_t)wid * F_)
                                     : (s2 + (size_t)(wid - B_ * L_) * F_);
  float2 v = ((const float2*)src)[lane];
  float s = v.x * v.x + v.y * v.y;
#pragma unroll
  for (int o = 32; o > 0; o >>= 1) s += __shfl_xor(s, o, 64);
  if (lane == 0) nrm[wid] = s;
}

// cost matrix -> bf16, two skewed streams per batch (one per dtw compute wave):
// global row r: w = r>>9, rl = r&511; element (r, col c) stored at
// stream[(b*2+w)][u = c + 4*(rl>>3)][rl].  Lane l of dtw wave w reads
// rl = 8l..8l+7 -> one contiguous uint4 per (u, lane): coalesced 1KB/wave.
__global__ __launch_bounds__(256) void cost_kernel(const float* __restrict__ s1,
                                                   const float* __restrict__ s2,
                                                   ushort* __restrict__ stream,
                                                   const float* __restrict__ nrm) {
  __shared__ short aL[128][136];
  __shared__ short bL[128][136];
  __shared__ float q1[128], q2[128];

  const int tid = threadIdx.x;
  const int b   = blockIdx.y;
  const int tc  = blockIdx.x & 7;
  const int tr  = blockIdx.x >> 3;

  const float* Ap = s1 + (size_t)b * L_ * F_ + (size_t)tr * 128 * F_;
  const float* Bp = s2 + (size_t)b * L_ * F_ + (size_t)tc * 128 * F_;

#pragma unroll 4
  for (int it = 0; it < 16; ++it) {
    int idx = it * 1024 + tid * 4;
    int r = idx >> 7, cc = idx & 127;
    float4 va = *(const float4*)(Ap + idx);
    float4 vb = *(const float4*)(Bp + idx);
    *(uint2*)&aL[r][cc] = make_uint2(pack2(va.x, va.y), pack2(va.z, va.w));
    *(uint2*)&bL[r][cc] = make_uint2(pack2(vb.x, vb.y), pack2(vb.z, vb.w));
  }
  if (tid < 128) q1[tid] = nrm[(size_t)b * L_ + tr * 128 + tid];
  else           q2[tid - 128] = nrm[(size_t)B_ * L_ + (size_t)b * L_ + tc * 128 + (tid - 128)];
  __syncthreads();

  const int wave = tid >> 6, lane = tid & 63, quad = lane >> 4, l16 = lane & 15;
  const int m0 = (wave >> 1) * 64, n0 = (wave & 1) * 64;

  f32x4 acc[4][4] = {};
#pragma unroll
  for (int kc = 0; kc < 4; ++kc) {
    short8 af[4], bf[4];
#pragma unroll
    for (int mi = 0; mi < 4; ++mi)
      af[mi] = *(const short8*)&aL[m0 + mi * 16 + l16][kc * 32 + quad * 8];
#pragma unroll
    for (int nj = 0; nj < 4; ++nj)
      bf[nj] = *(const short8*)&bL[n0 + nj * 16 + l16][kc * 32 + quad * 8];
#pragma unroll
    for (int mi = 0; mi < 4; ++mi)
#pragma unroll
      for (int nj = 0; nj < 4; ++nj)
        acc[mi][nj] = __builtin_amdgcn_mfma_f32_16x16x32_bf16(af[mi], bf[nj], acc[mi][nj], 0, 0, 0);
  }

  ushort* Sb = stream + (size_t)(b * 2) * UDIM_ * 512;
#pragma unroll
  for (int mi = 0; mi < 4; ++mi)
#pragma unroll
    for (int nj = 0; nj < 4; ++nj) {
      int lr0 = m0 + mi * 16 + quad * 4;
      int lc  = n0 + nj * 16 + l16;
      int r0  = tr * 128 + lr0;   // 4-aligned: rows r0..r0+3 share (rl>>3)
      int c   = tc * 128 + lc;
      float vx = sqrtf(fmaxf(q1[lr0 + 0] + q2[lc] - 2.0f * acc[mi][nj][0], 0.0f));
      float vy = sqrtf(fmaxf(q1[lr0 + 1] + q2[lc] - 2.0f * acc[mi][nj][1], 0.0f));
      float vz = sqrtf(fmaxf(q1[lr0 + 2] + q2[lc] - 2.0f * acc[mi][nj][2], 0.0f));
      float vw = sqrtf(fmaxf(q1[lr0 + 3] + q2[lc] - 2.0f * acc[mi][nj][3], 0.0f));
      int w  = r0 >> 9;
      int rl = r0 & 511;
      int u  = c + 4 * (rl >> 3);
      ushort* p = Sb + ((size_t)w * UDIM_ + u) * 512 + rl;
      *(uint2*)p = make_uint2(pack2(vx, vy), pack2(vz, vw));
    }
}

// One block per batch, 2 waves, no LDS staging:
//   wave0: DTW rows 0..511   (8 rows/lane), local steps 0..1279; writes hand[]
//   wave1: DTW rows 512..1023, lagging LAG_; reads hand[] via 4-deep register ring
// Costs arrive via a 16-deep register ring of direct coalesced global uint4
// loads (in-order vmcnt; data written by cost_kernel, so no intra-kernel
// ordering needed). Barriers every 16 steps only for the hand[] handoff.
__global__ __launch_bounds__(128, 1) void dtw_kernel(const ushort* __restrict__ stream,
                                                     float* __restrict__ out) {
  __shared__ float hand[1024];  // row-511 D values by column

  const int b    = blockIdx.x;
  const int tid  = threadIdx.x;
  const int wave = tid >> 6;
  const int lane = tid & 63;
  const bool l0 = (lane == 0);

  const ushort* srcW = stream + (size_t)(b * 2 + wave) * UDIM_ * 512 + lane * 8;

  // prime the global-load ring with u-rows 0..15 (kernel-start: data already in HBM)
  uint4 ring[16];
#pragma unroll
  for (int i = 0; i < 16; ++i) ring[i] = *(const uint4*)(srcW + (size_t)i * 512);

  float left[8];
#pragma unroll
  for (int r = 0; r < 8; ++r) left[r] = BIGV;
  float bot = BIGV;
  float sh[4] = {BIGV, BIGV, BIGV, BIGV};
  float hPrev = BIGV, result = 0.0f;
  float hRing[4];

  for (int n = 0; n < NSEGG_; ++n) {
    __syncthreads();  // hand[] writes >=2 phases old are visible
    const int sBase = 16 * n - (wave ? LAG_ : 0);
    if ((unsigned)sBase >= 1280u) continue;  // idle phase (barrier already hit)

    if (wave == 1) {
#pragma unroll
      for (int i = 0; i < 4; ++i) hRing[i] = hand[(sBase + i) & 1023];
    }

#pragma unroll
    for (int k = 0; k < 16; ++k) {
      const int s = sBase + k;          // local step; s & 15 == k (LAG_ % 16 == 0)
      const int col = s - S_ * lane;
      float shN = __shfl_up(bot, 1, 64);
      float hCur = (wave == 1) ? hRing[k & 3] : 0.0f;

      uint4 cw = ring[k];
      ring[k] = *(const uint4*)(srcW + (size_t)(s + 16) * 512);  // u <= 1295 < UDIM_
      if (wave == 1) hRing[k & 3] = hand[(s + 4) & 1023];        // for step k+4

      float cv[8];
      cv[0] = __uint_as_float(cw.x << 16);
      cv[1] = __uint_as_float(cw.x & 0xFFFF0000u);
      cv[2] = __uint_as_float(cw.y << 16);
      cv[3] = __uint_as_float(cw.y & 0xFFFF0000u);
      cv[4] = __uint_as_float(cw.z << 16);
      cv[5] = __uint_as_float(cw.z & 0xFFFF0000u);
      cv[6] = __uint_as_float(cw.w << 16);
      cv[7] = __uint_as_float(cw.w & 0xFFFF0000u);

      // shfl ring: slot written at step t read as diag at t+4, as up at t+3
      float dgT, upT;
      if (wave == 0) {
        dgT = l0 ? ((s == 0) ? 0.0f : BIGV) : sh[k & 3];
        upT = l0 ? BIGV : sh[(k + 1) & 3];
      } else {
        dgT = l0 ? ((s == 0) ? BIGV : hPrev) : sh[k & 3];
        upT = l0 ? hCur : sh[(k + 1) & 3];
      }
      bool act = ((unsigned)col < 1024u);
      float c0 = act ? cv[0] : BIGV;  // head-only mask; induction keeps
                                      // inactive-lane state >= ~1e9
      float cur = c0 + fminf(fminf(dgT, upT), left[0]);
      float nl[8];
      nl[0] = cur;
#pragma unroll
      for (int r = 1; r < 8; ++r) {
        cur = cv[r] + fminf(fminf(left[r - 1], left[r]), cur);  // v_min3 + v_add
        nl[r] = cur;
      }
#pragma unroll
      for (int r = 0; r < 8; ++r) left[r] = nl[r];
      bot = nl[7];
      sh[k & 3] = shN;
      hPrev = hCur;

      if (wave == 0) {
        int j = s - 252;  // lane63's column this step
        if (lane == 63 && (unsigned)j < 1024u) hand[j] = bot;
      } else if (s == 1275) {
        result = bot;  // lane63 at col 1023: D[1024][1024]
      }
    }
  }
  if (wave == 1 && lane == 63) out[b] = 1.0f / (1.0f + result * (1.0f / 2048.0f));
}

extern "C" void kernel_launch(void* const* d_in, const int* in_sizes, int n_in,
                              void* d_out, int out_size, void* d_ws, size_t ws_size,
                              hipStream_t stream_) {
  const float* s1 = (const float*)d_in[0];
  const float* s2 = (const float*)d_in[1];
  float* out = (float*)d_out;
  ushort* cws = (ushort*)d_ws;
  float* nrm = (float*)(cws + STREAM_US);

  norm_kernel<<<dim3((2 * B_ * L_) / 4), 256, 0, stream_>>>(s1, s2, nrm);
  cost_kernel<<<dim3(64, B_), 256, 0, stream_>>>(s1, s2, cws, nrm);
  dtw_kernel<<<dim3(B_), 128, 0, stream_>>>(cws, out);
}

// Round 9
// 244.729 us; speedup vs baseline: 1.5012x; 1.5012x over previous
//
#include <hip/hip_runtime.h>
#include <hip/hip_bf16.h>

#define BIGV 1.0e9f

static constexpr int B_ = 32;
static constexpr int L_ = 1024;
static constexpr int F_ = 128;
static constexpr int S_ = 4;          // in-wave lane stagger (columns)
static constexpr int UDIM_ = 1296;    // skewed u-rows per stream (1275 used + slack)
static constexpr int LAG_ = 288;      // wave1 local-step lag (18 phases)
static constexpr int NSEGL_ = 80;     // local phases per wave (1280 steps)
static constexpr int NSEGG_ = 98;     // global phases (1568 steps)
static constexpr size_t STREAM_US = (size_t)B_ * 2 * UDIM_ * 512;  // ushorts

typedef __attribute__((ext_vector_type(8))) short short8;
typedef __attribute__((ext_vector_type(4))) float f32x4;

__device__ __forceinline__ unsigned pack2(float x, float y) {
  union { float f; unsigned u; } a, b;
  a.f = x; b.f = y;
  unsigned lo = (a.u + 0x7FFFu + ((a.u >> 16) & 1u)) >> 16;
  unsigned hi = (b.u + 0x7FFFu + ((b.u >> 16) & 1u)) >> 16;
  return lo | (hi << 16);
}

// one wave per row of 128 floats; nrm[wid] = sum of squares
__global__ void norm_kernel(const float* __restrict__ s1, const float* __restrict__ s2,
                            float* __restrict__ nrm) {
  int gt   = blockIdx.x * blockDim.x + threadIdx.x;
  int wid  = gt >> 6;
  int lane = gt & 63;
  const float* src = (wid < B_ * L_) ? (s1 + (size_t)wid * F_)
                                     : (s2 + (size_t)(wid - B_ * L_) * F_);
  float2 v = ((const float2*)src)[lane];
  float s = v.x * v.x + v.y * v.y;
#pragma unroll
  for (int o = 32; o > 0; o >>= 1) s += __shfl_xor(s, o, 64);
  if (lane == 0) nrm[wid] = s;
}

// cost matrix -> bf16, two skewed streams per batch (one per dtw compute wave):
// global row r: w = r>>9, rl = r&511; element (r, col c) stored at
// stream[(b*2+w)][u = c + 4*(rl>>3)][rl].
__global__ __launch_bounds__(256) void cost_kernel(const float* __restrict__ s1,
                                                   const float* __restrict__ s2,
                                                   ushort* __restrict__ stream,
                                                   const float* __restrict__ nrm) {
  __shared__ short aL[128][136];
  __shared__ short bL[128][136];
  __shared__ float q1[128], q2[128];

  const int tid = threadIdx.x;
  const int b   = blockIdx.y;
  const int tc  = blockIdx.x & 7;
  const int tr  = blockIdx.x >> 3;

  const float* Ap = s1 + (size_t)b * L_ * F_ + (size_t)tr * 128 * F_;
  const float* Bp = s2 + (size_t)b * L_ * F_ + (size_t)tc * 128 * F_;

#pragma unroll 4
  for (int it = 0; it < 16; ++it) {
    int idx = it * 1024 + tid * 4;
    int r = idx >> 7, cc = idx & 127;
    float4 va = *(const float4*)(Ap + idx);
    float4 vb = *(const float4*)(Bp + idx);
    *(uint2*)&aL[r][cc] = make_uint2(pack2(va.x, va.y), pack2(va.z, va.w));
    *(uint2*)&bL[r][cc] = make_uint2(pack2(vb.x, vb.y), pack2(vb.z, vb.w));
  }
  if (tid < 128) q1[tid] = nrm[(size_t)b * L_ + tr * 128 + tid];
  else           q2[tid - 128] = nrm[(size_t)B_ * L_ + (size_t)b * L_ + tc * 128 + (tid - 128)];
  __syncthreads();

  const int wave = tid >> 6, lane = tid & 63, quad = lane >> 4, l16 = lane & 15;
  const int m0 = (wave >> 1) * 64, n0 = (wave & 1) * 64;

  f32x4 acc[4][4] = {};
#pragma unroll
  for (int kc = 0; kc < 4; ++kc) {
    short8 af[4], bf[4];
#pragma unroll
    for (int mi = 0; mi < 4; ++mi)
      af[mi] = *(const short8*)&aL[m0 + mi * 16 + l16][kc * 32 + quad * 8];
#pragma unroll
    for (int nj = 0; nj < 4; ++nj)
      bf[nj] = *(const short8*)&bL[n0 + nj * 16 + l16][kc * 32 + quad * 8];
#pragma unroll
    for (int mi = 0; mi < 4; ++mi)
#pragma unroll
      for (int nj = 0; nj < 4; ++nj)
        acc[mi][nj] = __builtin_amdgcn_mfma_f32_16x16x32_bf16(af[mi], bf[nj], acc[mi][nj], 0, 0, 0);
  }

  ushort* Sb = stream + (size_t)(b * 2) * UDIM_ * 512;
#pragma unroll
  for (int mi = 0; mi < 4; ++mi)
#pragma unroll
    for (int nj = 0; nj < 4; ++nj) {
      int lr0 = m0 + mi * 16 + quad * 4;
      int lc  = n0 + nj * 16 + l16;
      int r0  = tr * 128 + lr0;   // 4-aligned: rows r0..r0+3 share (rl>>3)
      int c   = tc * 128 + lc;
      float vx = sqrtf(fmaxf(q1[lr0 + 0] + q2[lc] - 2.0f * acc[mi][nj][0], 0.0f));
      float vy = sqrtf(fmaxf(q1[lr0 + 1] + q2[lc] - 2.0f * acc[mi][nj][1], 0.0f));
      float vz = sqrtf(fmaxf(q1[lr0 + 2] + q2[lc] - 2.0f * acc[mi][nj][2], 0.0f));
      float vw = sqrtf(fmaxf(q1[lr0 + 3] + q2[lc] - 2.0f * acc[mi][nj][3], 0.0f));
      int w  = r0 >> 9;
      int rl = r0 & 511;
      int u  = c + 4 * (rl >> 3);
      ushort* p = Sb + ((size_t)w * UDIM_ + u) * 512 + rl;
      *(uint2*)p = make_uint2(pack2(vx, vy), pack2(vz, vw));
    }
}

#define UNPACK_CV(cw, cv)                         \
  cv[0] = __uint_as_float((cw).x << 16);          \
  cv[1] = __uint_as_float((cw).x & 0xFFFF0000u);  \
  cv[2] = __uint_as_float((cw).y << 16);          \
  cv[3] = __uint_as_float((cw).y & 0xFFFF0000u);  \
  cv[4] = __uint_as_float((cw).z << 16);          \
  cv[5] = __uint_as_float((cw).z & 0xFFFF0000u);  \
  cv[6] = __uint_as_float((cw).w << 16);          \
  cv[7] = __uint_as_float((cw).w & 0xFFFF0000u);

#define CHAIN_BODY(head)                                            \
  {                                                                 \
    float cur = (head);                                             \
    float nl[8];                                                    \
    nl[0] = cur;                                                    \
    _Pragma("unroll") for (int r = 1; r < 8; ++r) {                 \
      cur = cv[r] + fminf(fminf(left[r - 1], left[r]), cur);        \
      nl[r] = cur;                                                  \
    }                                                               \
    _Pragma("unroll") for (int r = 0; r < 8; ++r) left[r] = nl[r];  \
    bot = nl[7];                                                    \
  }

// One block per batch, 4 waves (R7-proven structure):
//   wave0: DTW rows 0..511 (8 rows/lane); writes hand[] (batched b128 in fast phases)
//   wave1: DTW rows 512..1023, lag LAG_; reads hand[] via 4-deep register ring
//   wave2/3: loaders staging stream0/stream1 u-rows into double-buffered LDS segs
// Fast phases (sBase in [256,1008]): all lanes active -> no masks, no per-step
// predication. Guard phases: exact R7 semantics.
__global__ __launch_bounds__(256, 1) void dtw_kernel(const ushort* __restrict__ stream,
                                                     float* __restrict__ out) {
  __shared__ ushort ldsA[2][16][512];  // 32 KB, wave0 stream
  __shared__ ushort ldsB[2][16][512];  // 32 KB, wave1 stream
  __shared__ float hand[1040];         // row-511 D values; +16 slack for unmasked prefetch

  const int b    = blockIdx.x;
  const int tid  = threadIdx.x;
  const int wave = tid >> 6;
  const int lane = tid & 63;

  if (wave >= 2) {
    // ---------------- loader waves ----------------
    const int ls = wave - 2;  // 0 -> stream A, 1 -> stream B
    const ushort* src = stream + (size_t)(b * 2 + ls) * UDIM_ * 512;
    auto loadSeg = [&](int g, int buf) {
      ushort(*dst)[512] = ls ? ldsB[buf] : ldsA[buf];
#pragma unroll
      for (int i = 0; i < 16; ++i) {
        const uint4* sp = (const uint4*)(src + (size_t)(g * 16 + i) * 512);
        *(uint4*)&dst[i][lane * 8] = sp[lane];
      }
    };
    if (ls == 0) loadSeg(0, 0);  // preload wave0 seg 0
    for (int n = 0; n < NSEGG_; ++n) {
      __syncthreads();
      int g = (ls == 0) ? (n + 1) : (n - 17);  // B's local seg m+1 = n-17
      if ((unsigned)g < (unsigned)NSEGL_) loadSeg(g, g & 1);
    }
    return;
  }

  // ---------------- compute waves ----------------
  const bool l0 = (lane == 0);
  float left[8];
#pragma unroll
  for (int r = 0; r < 8; ++r) left[r] = BIGV;
  float bot = BIGV;
  float sh[4] = {BIGV, BIGV, BIGV, BIGV};
  float hPrev = BIGV, result = 0.0f;
  float hRing[4];
  float hb[16];
  uint4 pre[4];

  for (int n = 0; n < NSEGG_; ++n) {
    __syncthreads();  // hand[] writes >=1 phase old visible; loader seg published
    const int sBase = 16 * n - (wave ? LAG_ : 0);
    if ((unsigned)sBase >= 1280u) continue;  // idle phase (barrier already hit)

    const ushort(*lds)[512] = wave ? ldsB[(sBase >> 4) & 1] : ldsA[(sBase >> 4) & 1];
#pragma unroll
    for (int i = 0; i < 4; ++i) pre[i] = *(const uint4*)&lds[i][lane * 8];

    const bool fast = (sBase >= 256) & (sBase <= 1008);

    if (wave == 0) {
      if (fast) {
#pragma unroll
        for (int k = 0; k < 16; ++k) {
          float shN = __shfl_up(bot, 1, 64);
          uint4 cw = pre[k & 3];
          if (k < 12) pre[k & 3] = *(const uint4*)&lds[k + 4][lane * 8];
          float cv[8];
          UNPACK_CV(cw, cv)
          float dgT = l0 ? BIGV : sh[k & 3];
          float upT = l0 ? BIGV : sh[(k + 1) & 3];
          CHAIN_BODY(cv[0] + fminf(fminf(dgT, upT), left[0]))
          sh[k & 3] = shN;
          hb[k] = bot;
        }
        if (lane == 63) {  // batched hand write: j = sBase-252 .. +15 (all valid)
          float4* hp = (float4*)&hand[sBase - 252];
          hp[0] = make_float4(hb[0], hb[1], hb[2], hb[3]);
          hp[1] = make_float4(hb[4], hb[5], hb[6], hb[7]);
          hp[2] = make_float4(hb[8], hb[9], hb[10], hb[11]);
          hp[3] = make_float4(hb[12], hb[13], hb[14], hb[15]);
        }
      } else {
#pragma unroll
        for (int k = 0; k < 16; ++k) {
          const int s = sBase + k;
          const int col = s - S_ * lane;
          float shN = __shfl_up(bot, 1, 64);
          uint4 cw = pre[k & 3];
          if (k < 12) pre[k & 3] = *(const uint4*)&lds[k + 4][lane * 8];
          float cv[8];
          UNPACK_CV(cw, cv)
          float dgT = l0 ? ((s == 0) ? 0.0f : BIGV) : sh[k & 3];
          float upT = l0 ? BIGV : sh[(k + 1) & 3];
          bool act = ((unsigned)col < 1024u);
          float c0 = act ? cv[0] : BIGV;  // head-only mask; induction keeps
                                          // inactive-lane state >= ~1e9
          CHAIN_BODY(c0 + fminf(fminf(dgT, upT), left[0]))
          sh[k & 3] = shN;
          int j = s - 252;  // lane63's column this step
          if (lane == 63 && (unsigned)j < 1024u) hand[j] = bot;
        }
      }
    } else {
      if (fast) {
#pragma unroll
        for (int i = 0; i < 4; ++i) hRing[i] = hand[sBase + i];
#pragma unroll
        for (int k = 0; k < 16; ++k) {
          float shN = __shfl_up(bot, 1, 64);
          float hCur = hRing[k & 3];
          uint4 cw = pre[k & 3];
          if (k < 12) pre[k & 3] = *(const uint4*)&lds[k + 4][lane * 8];
          hRing[k & 3] = hand[sBase + k + 4];  // <= 1027 < 1040, in-bounds
          float cv[8];
          UNPACK_CV(cw, cv)
          float dgT = l0 ? hPrev : sh[k & 3];
          float upT = l0 ? hCur : sh[(k + 1) & 3];
          CHAIN_BODY(cv[0] + fminf(fminf(dgT, upT), left[0]))
          sh[k & 3] = shN;
          hPrev = hCur;
        }
      } else {
#pragma unroll
        for (int i = 0; i < 4; ++i) hRing[i] = hand[(sBase + i) & 1023];
#pragma unroll
        for (int k = 0; k < 16; ++k) {
          const int s = sBase + k;
          const int col = s - S_ * lane;
          float shN = __shfl_up(bot, 1, 64);
          float hCur = hRing[k & 3];
          uint4 cw = pre[k & 3];
          if (k < 12) pre[k & 3] = *(const uint4*)&lds[k + 4][lane * 8];
          hRing[k & 3] = hand[(s + 4) & 1023];
          float cv[8];
          UNPACK_CV(cw, cv)
          float dgT = l0 ? ((s == 0) ? BIGV : hPrev) : sh[k & 3];
          float upT = l0 ? hCur : sh[(k + 1) & 3];
          bool act = ((unsigned)col < 1024u);
          float c0 = act ? cv[0] : BIGV;
          CHAIN_BODY(c0 + fminf(fminf(dgT, upT), left[0]))
          sh[k & 3] = shN;
          hPrev = hCur;
          if (s == 1275) result = bot;  // lane63 at col 1023: D[1024][1024]
        }
      }
    }
  }
  if (wave == 1 && lane == 63) out[b] = 1.0f / (1.0f + result * (1.0f / 2048.0f));
}

extern "C" void kernel_launch(void* const* d_in, const int* in_sizes, int n_in,
                              void* d_out, int out_size, void* d_ws, size_t ws_size,
                              hipStream_t stream_) {
  const float* s1 = (const float*)d_in[0];
  const float* s2 = (const float*)d_in[1];
  float* out = (float*)d_out;
  ushort* cws = (ushort*)d_ws;
  float* nrm = (float*)(cws + STREAM_US);

  norm_kernel<<<dim3((2 * B_ * L_) / 4), 256, 0, stream_>>>(s1, s2, nrm);
  cost_kernel<<<dim3(64, B_), 256, 0, stream_>>>(s1, s2, cws, nrm);
  dtw_kernel<<<dim3(B_), 256, 0, stream_>>>(cws, out);
}